// Round 13
// baseline (500.853 us; speedup 1.0000x reference)
//
#include <hip/hip_runtime.h>
#include <stdint.h>

// Workspace layout (bytes):
//   [0, 64Mi)            h: coarse activations [b][cell][ic:32]
//   [64Mi, +512Ki)       maskw: 1 bit per fine voxel, word = (b<<16)|(voxel>>5)
//   [+4B @ CNT_OFF]      counter (compact voxel count)
//   [BASE_OFF, +512Ki)   basew: per-mask-word exclusive base index into wl/vals
//   [WL_OFF, +1Mi)       wl: compact voxel ids (b<<21|z<<14|y<<7|x)
//   [VALS_OFF, +16Mi)    vals: [oc:16][PITCH] precomputed deconv outputs
#define H_BYTES   ((size_t)67108864)
#define MASK_OFF  ((size_t)67108864)
#define CNT_OFF   ((size_t)67633152)
#define BASE_OFF  ((size_t)67633408)
#define WL_OFF    ((size_t)68157696)
#define VALS_OFF  ((size_t)69206272)
#define PITCH     262144
#define NWORDS    131072

typedef float f32x4 __attribute__((ext_vector_type(4)));

__global__ __launch_bounds__(256) void scn_scatter_conv1(
    const float* __restrict__ feat, const float* __restrict__ W1,
    const int* __restrict__ coors, float* __restrict__ h,
    uint32_t* __restrict__ maskw, int npts)
{
    __shared__ float Ws[8 * 16 * 32];
    for (int i = threadIdx.x; i < 4096; i += 256) {
        // W1: [ic:32][cin:16][p:8] -> Ws[p][cin][ic]
        int ic = i >> 7, rem = i & 127, cin = rem >> 3, p = rem & 7;
        Ws[(p << 9) | (cin << 5) | ic] = W1[i];
    }
    __syncthreads();

    int total = npts * 32;
    for (int idx = blockIdx.x * 256 + threadIdx.x; idx < total;
         idx += gridDim.x * 256) {
        int pid = idx >> 5, ic = idx & 31;
        int b = coors[pid * 4 + 0];
        int z = coors[pid * 4 + 1];
        int y = coors[pid * 4 + 2];
        int x = coors[pid * 4 + 3];
        int p = ((z & 1) << 2) | ((y & 1) << 1) | (x & 1);

        const f32x4* f4 = reinterpret_cast<const f32x4*>(feat + pid * 16);
        f32x4 a0 = f4[0], a1 = f4[1], a2 = f4[2], a3 = f4[3];

        const float* w = Ws + (p << 9) + ic;   // stride 32 over cin
        float s = 0.f;
        s += a0[0] * w[0 << 5];   s += a0[1] * w[1 << 5];
        s += a0[2] * w[2 << 5];   s += a0[3] * w[3 << 5];
        s += a1[0] * w[4 << 5];   s += a1[1] * w[5 << 5];
        s += a1[2] * w[6 << 5];   s += a1[3] * w[7 << 5];
        s += a2[0] * w[8 << 5];   s += a2[1] * w[9 << 5];
        s += a2[2] * w[10 << 5];  s += a2[3] * w[11 << 5];
        s += a3[0] * w[12 << 5];  s += a3[1] * w[13 << 5];
        s += a3[2] * w[14 << 5];  s += a3[3] * w[15 << 5];

        int cell = (b << 18) | ((z >> 1) << 12) | ((y >> 1) << 6) | (x >> 1);
        atomicAdd(&h[((size_t)cell << 5) | ic], s);

        if (ic == 0) {
            int voxel = (z << 14) | (y << 7) | x;
            atomicOr(&maskw[(b << 16) | (voxel >> 5)], 1u << (voxel & 31));
        }
    }
}

// Rank/select setup: per mask word, grab a base index and emit compact voxel ids.
__global__ __launch_bounds__(256) void scn_base_worklist(
    const uint32_t* __restrict__ maskw, uint32_t* __restrict__ basew,
    uint32_t* __restrict__ wl, uint32_t* __restrict__ cnt)
{
    int i = blockIdx.x * 256 + threadIdx.x;
    if (i >= NWORDS) return;
    uint32_t w = maskw[i];
    if (!w) return;
    int n = __popc(w);
    uint32_t b = atomicAdd(cnt, (uint32_t)n);
    basew[i] = b;
    uint32_t vbase = (uint32_t)i << 5;   // (b<<21)|(z<<14)|(y<<7)|(x&~31)
    while (w) {
        int bit = __ffs(w) - 1;
        wl[b++] = vbase | (uint32_t)bit;
        w &= w - 1;
    }
}

// One thread per compact voxel: load h[cell] ONCE (128 B), compute all 16 oc.
__global__ __launch_bounds__(256) void scn_compute_vals(
    const float* __restrict__ h, const float* __restrict__ W2,
    const uint32_t* __restrict__ wl, const uint32_t* __restrict__ cnt,
    float* __restrict__ vals)
{
    // W2: [oc:16][ic:32][p:8] -> Ws[p*529 + ic*16 + oc]
    // plane stride 529: (529 mod 32)=17 -> p*17 mod 32 distinct for p=0..7,
    // so the 8 per-wave broadcast groups land in 8 distinct banks.
    __shared__ float Ws[8 * 529];
    for (int i = threadIdx.x; i < 4096; i += 256) {
        int oc = i >> 8, rem = i & 255, ic = rem >> 3, p = rem & 7;
        Ws[p * 529 + (ic << 4) + oc] = W2[i];
    }
    __syncthreads();

    uint32_t n = *cnt;
    uint32_t i = blockIdx.x * 256 + threadIdx.x;
    if (i >= n) return;

    uint32_t v = wl[i];
    int b = v >> 21, z = (v >> 14) & 127, y = (v >> 7) & 127, x = v & 127;
    int p = (((z & 1) ^ 1) << 2) | (((y & 1) ^ 1) << 1) | ((x & 1) ^ 1);
    int cell = (b << 18) | ((z >> 1) << 12) | ((y >> 1) << 6) | (x >> 1);

    const f32x4* hc = reinterpret_cast<const f32x4*>(h + ((size_t)cell << 5));
    f32x4 hv[8];
    #pragma unroll
    for (int q = 0; q < 8; ++q) hv[q] = hc[q];

    const float* wp = Ws + p * 529;
    for (int oc = 0; oc < 16; ++oc) {
        float s = 0.f;
        #pragma unroll
        for (int q = 0; q < 8; ++q) {
            s += hv[q][0] * wp[((4 * q + 0) << 4) + oc];
            s += hv[q][1] * wp[((4 * q + 1) << 4) + oc];
            s += hv[q][2] * wp[((4 * q + 2) << 4) + oc];
            s += hv[q][3] * wp[((4 * q + 3) << 4) + oc];
        }
        vals[(size_t)oc * PITCH + i] = s;
    }
}

// Streaming fill: ONE thread per voxel4; mask word, nibble and ranks computed
// once and reused for all 16 channels; PLAIN L2-allocating stores (the single
// change vs round 10's NT version — full-line writeback, no partial-line RMW).
__global__ __launch_bounds__(256) void scn_fill_merge(
    const uint32_t* __restrict__ maskw, const uint32_t* __restrict__ basew,
    const float* __restrict__ vals, float* __restrict__ out)
{
    int voxel4 = blockIdx.x * 256 + threadIdx.x;   // 0..524287
    f32x4* out4 = reinterpret_cast<f32x4*>(out);
    const f32x4 zero = {0.f, 0.f, 0.f, 0.f};
    int bit0 = (voxel4 & 7) << 2;

    #pragma unroll
    for (int b = 0; b < 2; ++b) {
        int word = (b << 16) | (voxel4 >> 3);
        uint32_t mword = maskw[word];
        uint32_t nib = (mword >> bit0) & 0xFu;
        int obase = (b << 23) | voxel4;            // (b*16+oc)<<19 | voxel4

        if (!nib) {
            #pragma unroll
            for (int oc = 0; oc < 16; ++oc)
                out4[obase + (oc << 19)] = zero;
        } else {
            uint32_t base = basew[word];
            uint32_t r0 = base + __popc(mword & ((1u << (bit0 + 0)) - 1u));
            uint32_t r1 = base + __popc(mword & ((1u << (bit0 + 1)) - 1u));
            uint32_t r2 = base + __popc(mword & ((1u << (bit0 + 2)) - 1u));
            uint32_t r3 = base + __popc(mword & ((1u << (bit0 + 3)) - 1u));
            #pragma unroll
            for (int oc = 0; oc < 16; ++oc) {
                const float* voc = vals + ((size_t)oc << 18);
                f32x4 r = zero;
                if (nib & 1u) r[0] = voc[r0];
                if (nib & 2u) r[1] = voc[r1];
                if (nib & 4u) r[2] = voc[r2];
                if (nib & 8u) r[3] = voc[r3];
                out4[obase + (oc << 19)] = r;
            }
        }
    }
}

extern "C" void kernel_launch(void* const* d_in, const int* in_sizes, int n_in,
                              void* d_out, int out_size, void* d_ws, size_t ws_size,
                              hipStream_t stream) {
    const float* feat  = (const float*)d_in[0];
    const float* W1    = (const float*)d_in[1];
    const float* W2    = (const float*)d_in[2];
    const int*   coors = (const int*)d_in[3];
    float*       out   = (float*)d_out;

    char* ws = (char*)d_ws;
    float*    h     = (float*)ws;
    uint32_t* maskw = (uint32_t*)(ws + MASK_OFF);
    uint32_t* cnt   = (uint32_t*)(ws + CNT_OFF);
    uint32_t* basew = (uint32_t*)(ws + BASE_OFF);
    uint32_t* wl    = (uint32_t*)(ws + WL_OFF);
    float*    vals  = (float*)(ws + VALS_OFF);
    int npts = in_sizes[0] / 16;

    // Zero h + maskw + counter (basew/wl/vals fully written before any read).
    hipMemsetAsync(d_ws, 0, CNT_OFF + 256, stream);

    int t1 = npts * 32;
    int blocks1 = (t1 + 255) / 256;
    if (blocks1 > 4096) blocks1 = 4096;
    scn_scatter_conv1<<<blocks1, 256, 0, stream>>>(feat, W1, coors, h, maskw, npts);

    scn_base_worklist<<<NWORDS / 256, 256, 0, stream>>>(maskw, basew, wl, cnt);

    // One thread per compact voxel (cnt <= npts = 200k < 1024*256).
    scn_compute_vals<<<1024, 256, 0, stream>>>(h, W2, wl, cnt, vals);

    // One thread per voxel4: 524288 threads = 2048 blocks.
    scn_fill_merge<<<2048, 256, 0, stream>>>(maskw, basew, vals, out);
}

// Round 15
// 364.207 us; speedup vs baseline: 1.3752x; 1.3752x over previous
//
#include <hip/hip_runtime.h>
#include <stdint.h>

// Workspace layout (bytes):
//   [0, 64Mi)            h: coarse activations [b][cell][ic:32]
//   [64Mi, +512Ki)       maskw: 1 bit per fine voxel, word = (b<<16)|(voxel>>5)
//   [+4B @ CNT_OFF]      counter (compact voxel count)
//   [+1Ki @ BSUM_OFF]    bsum: 512 per-scan-block sums -> exclusive offsets
//   [BASE_OFF, +512Ki)   basew: per-mask-word exclusive prefix (MONOTONIC)
//   [WL_OFF, +1Mi)       wl: compact voxel ids (b<<21|z<<14|y<<7|x), sorted
//   [VALS_OFF, +16Mi)    vals: [oc:16][PITCH] precomputed deconv outputs
#define MASK_OFF  ((size_t)67108864)
#define CNT_OFF   ((size_t)67633152)
#define BSUM_OFF  ((size_t)67633408)
#define BASE_OFF  ((size_t)67637504)
#define WL_OFF    ((size_t)68161792)
#define VALS_OFF  ((size_t)69210368)
#define PITCH     262144
#define NWORDS    131072

typedef float f32x4 __attribute__((ext_vector_type(4)));

__global__ __launch_bounds__(256) void scn_scatter_conv1(
    const float* __restrict__ feat, const float* __restrict__ W1,
    const int* __restrict__ coors, float* __restrict__ h,
    uint32_t* __restrict__ maskw, int npts)
{
    __shared__ float Ws[8 * 16 * 32];
    for (int i = threadIdx.x; i < 4096; i += 256) {
        // W1: [ic:32][cin:16][p:8] -> Ws[p][cin][ic]
        int ic = i >> 7, rem = i & 127, cin = rem >> 3, p = rem & 7;
        Ws[(p << 9) | (cin << 5) | ic] = W1[i];
    }
    __syncthreads();

    int total = npts * 32;
    for (int idx = blockIdx.x * 256 + threadIdx.x; idx < total;
         idx += gridDim.x * 256) {
        int pid = idx >> 5, ic = idx & 31;
        int b = coors[pid * 4 + 0];
        int z = coors[pid * 4 + 1];
        int y = coors[pid * 4 + 2];
        int x = coors[pid * 4 + 3];
        int p = ((z & 1) << 2) | ((y & 1) << 1) | (x & 1);

        const f32x4* f4 = reinterpret_cast<const f32x4*>(feat + pid * 16);
        f32x4 a0 = f4[0], a1 = f4[1], a2 = f4[2], a3 = f4[3];

        const float* w = Ws + (p << 9) + ic;   // stride 32 over cin
        float s = 0.f;
        s += a0[0] * w[0 << 5];   s += a0[1] * w[1 << 5];
        s += a0[2] * w[2 << 5];   s += a0[3] * w[3 << 5];
        s += a1[0] * w[4 << 5];   s += a1[1] * w[5 << 5];
        s += a1[2] * w[6 << 5];   s += a1[3] * w[7 << 5];
        s += a2[0] * w[8 << 5];   s += a2[1] * w[9 << 5];
        s += a2[2] * w[10 << 5];  s += a2[3] * w[11 << 5];
        s += a3[0] * w[12 << 5];  s += a3[1] * w[13 << 5];
        s += a3[2] * w[14 << 5];  s += a3[3] * w[15 << 5];

        int cell = (b << 18) | ((z >> 1) << 12) | ((y >> 1) << 6) | (x >> 1);
        atomicAdd(&h[((size_t)cell << 5) | ic], s);

        if (ic == 0) {
            int voxel = (z << 14) | (y << 7) | x;
            atomicOr(&maskw[(b << 16) | (voxel >> 5)], 1u << (voxel & 31));
        }
    }
}

// ---- 3-kernel exclusive prefix scan over per-word popcounts (monotonic basew)
__global__ __launch_bounds__(256) void scn_scan1(
    const uint32_t* __restrict__ maskw, uint32_t* __restrict__ bsum)
{
    __shared__ uint32_t red[256];
    int t = threadIdx.x;
    red[t] = __popc(maskw[blockIdx.x * 256 + t]);
    __syncthreads();
    for (int s = 128; s > 0; s >>= 1) {
        if (t < s) red[t] += red[t + s];
        __syncthreads();
    }
    if (t == 0) bsum[blockIdx.x] = red[0];
}

__global__ __launch_bounds__(512) void scn_scan2(
    uint32_t* __restrict__ bsum, uint32_t* __restrict__ cnt)
{
    __shared__ uint32_t v[512];
    int t = threadIdx.x;
    v[t] = bsum[t];
    __syncthreads();
    for (int off = 1; off < 512; off <<= 1) {
        uint32_t x = v[t];
        uint32_t y = (t >= off) ? v[t - off] : 0;
        __syncthreads();
        v[t] = x + y;
        __syncthreads();
    }
    bsum[t] = t ? v[t - 1] : 0;        // exclusive
    if (t == 511) *cnt = v[511];
}

__global__ __launch_bounds__(256) void scn_scan3(
    const uint32_t* __restrict__ maskw, const uint32_t* __restrict__ bsum,
    uint32_t* __restrict__ basew, uint32_t* __restrict__ wl)
{
    __shared__ uint32_t v[256];
    int t = threadIdx.x;
    int i = blockIdx.x * 256 + t;
    uint32_t w = maskw[i];
    v[t] = __popc(w);
    __syncthreads();
    for (int off = 1; off < 256; off <<= 1) {
        uint32_t x = v[t];
        uint32_t y = (t >= off) ? v[t - off] : 0;
        __syncthreads();
        v[t] = x + y;
        __syncthreads();
    }
    uint32_t base = bsum[blockIdx.x] + (t ? v[t - 1] : 0);
    basew[i] = base;
    uint32_t vb = (uint32_t)i << 5;    // (b<<21)|(z<<14)|(y<<7)|(x&~31)
    while (w) {
        int bit = __ffs(w) - 1;
        wl[base++] = vb | (uint32_t)bit;
        w &= w - 1;
    }
}

// One thread per compact voxel: load h[cell] ONCE (128 B), compute all 16 oc.
__global__ __launch_bounds__(256) void scn_compute_vals(
    const float* __restrict__ h, const float* __restrict__ W2,
    const uint32_t* __restrict__ wl, const uint32_t* __restrict__ cnt,
    float* __restrict__ vals)
{
    // W2: [oc:16][ic:32][p:8] -> Ws[p*529 + ic*16 + oc]
    __shared__ float Ws[8 * 529];
    for (int i = threadIdx.x; i < 4096; i += 256) {
        int oc = i >> 8, rem = i & 255, ic = rem >> 3, p = rem & 7;
        Ws[p * 529 + (ic << 4) + oc] = W2[i];
    }
    __syncthreads();

    uint32_t n = *cnt;
    uint32_t i = blockIdx.x * 256 + threadIdx.x;
    if (i >= n) return;

    uint32_t v = wl[i];
    int b = v >> 21, z = (v >> 14) & 127, y = (v >> 7) & 127, x = v & 127;
    int p = (((z & 1) ^ 1) << 2) | (((y & 1) ^ 1) << 1) | ((x & 1) ^ 1);
    int cell = (b << 18) | ((z >> 1) << 12) | ((y >> 1) << 6) | (x >> 1);

    const f32x4* hc = reinterpret_cast<const f32x4*>(h + ((size_t)cell << 5));
    f32x4 hv[8];
    #pragma unroll
    for (int q = 0; q < 8; ++q) hv[q] = hc[q];

    const float* wp = Ws + p * 529;
    for (int oc = 0; oc < 16; ++oc) {
        float s = 0.f;
        #pragma unroll
        for (int q = 0; q < 8; ++q) {
            s += hv[q][0] * wp[((4 * q + 0) << 4) + oc];
            s += hv[q][1] * wp[((4 * q + 1) << 4) + oc];
            s += hv[q][2] * wp[((4 * q + 2) << 4) + oc];
            s += hv[q][3] * wp[((4 * q + 3) << 4) + oc];
        }
        vals[(size_t)oc * PITCH + i] = s;
    }
}

// Streaming fill: block = contiguous 2048-float4 span of ONE plane. All mask
// words, bases, and this span's vals staged to LDS first; the store loop has
// ZERO global loads -> no vmcnt drains -> stores stream at fill rate.
__global__ __launch_bounds__(256) void scn_fill_merge(
    const uint32_t* __restrict__ maskw, const uint32_t* __restrict__ basew,
    const float* __restrict__ vals, float* __restrict__ out)
{
    __shared__ uint32_t s_mask[256];
    __shared__ uint32_t s_base[256];
    __shared__ float    s_vals[8192];   // worst case: 256 words fully occupied

    int tid   = threadIdx.x;
    int chunk = blockIdx.x;            // 0..8191
    int chan  = chunk >> 8;            // b*16 + oc
    int c     = chunk & 255;           // which 2048-float4 chunk of the plane
    int b     = chan >> 4;
    int oc    = chan & 15;

    int w0 = (b << 16) | (c << 8);     // first global mask word of this chunk
    s_mask[tid] = maskw[w0 + tid];
    s_base[tid] = basew[w0 + tid];
    __syncthreads();

    uint32_t vbase = s_base[0];
    uint32_t vend  = s_base[255] + __popc(s_mask[255]);
    int n = (int)(vend - vbase);
    const float* voc = vals + ((size_t)oc << 18);   // PITCH = 1<<18
    for (int i = tid; i < n; i += 256) s_vals[i] = voc[vbase + i];
    __syncthreads();

    f32x4* out4 = reinterpret_cast<f32x4*>(out) + ((size_t)chan << 19)
                + (size_t)c * 2048;
    #pragma unroll
    for (int it = 0; it < 8; ++it) {
        int lv4 = it * 256 + tid;                   // 0..2047
        uint32_t mword = s_mask[lv4 >> 3];
        int bit0 = (lv4 & 7) << 2;
        uint32_t nib = (mword >> bit0) & 0xFu;
        f32x4 r = {0.f, 0.f, 0.f, 0.f};
        if (nib) {
            uint32_t base = s_base[lv4 >> 3] - vbase;
            if (nib & 1u) r[0] = s_vals[base + __popc(mword & ((1u << (bit0 + 0)) - 1u))];
            if (nib & 2u) r[1] = s_vals[base + __popc(mword & ((1u << (bit0 + 1)) - 1u))];
            if (nib & 4u) r[2] = s_vals[base + __popc(mword & ((1u << (bit0 + 2)) - 1u))];
            if (nib & 8u) r[3] = s_vals[base + __popc(mword & ((1u << (bit0 + 3)) - 1u))];
        }
        out4[lv4] = r;
    }
}

extern "C" void kernel_launch(void* const* d_in, const int* in_sizes, int n_in,
                              void* d_out, int out_size, void* d_ws, size_t ws_size,
                              hipStream_t stream) {
    const float* feat  = (const float*)d_in[0];
    const float* W1    = (const float*)d_in[1];
    const float* W2    = (const float*)d_in[2];
    const int*   coors = (const int*)d_in[3];
    float*       out   = (float*)d_out;

    char* ws = (char*)d_ws;
    float*    h     = (float*)ws;
    uint32_t* maskw = (uint32_t*)(ws + MASK_OFF);
    uint32_t* cnt   = (uint32_t*)(ws + CNT_OFF);
    uint32_t* bsum  = (uint32_t*)(ws + BSUM_OFF);
    uint32_t* basew = (uint32_t*)(ws + BASE_OFF);
    uint32_t* wl    = (uint32_t*)(ws + WL_OFF);
    float*    vals  = (float*)(ws + VALS_OFF);
    int npts = in_sizes[0] / 16;

    // Zero h + maskw (scan kernels fully write cnt/bsum/basew/wl; vals
    // fully written for i < cnt before merge reads them).
    hipMemsetAsync(d_ws, 0, CNT_OFF, stream);

    int t1 = npts * 32;
    int blocks1 = (t1 + 255) / 256;
    if (blocks1 > 4096) blocks1 = 4096;
    scn_scatter_conv1<<<blocks1, 256, 0, stream>>>(feat, W1, coors, h, maskw, npts);

    scn_scan1<<<NWORDS / 256, 256, 0, stream>>>(maskw, bsum);
    scn_scan2<<<1, 512, 0, stream>>>(bsum, cnt);
    scn_scan3<<<NWORDS / 256, 256, 0, stream>>>(maskw, bsum, basew, wl);

    // One thread per compact voxel (cnt <= npts = 200k < 1024*256).
    scn_compute_vals<<<1024, 256, 0, stream>>>(h, W2, wl, cnt, vals);

    // 8192 blocks: one contiguous 2048-float4 plane chunk each.
    scn_fill_merge<<<8192, 256, 0, stream>>>(maskw, basew, vals, out);
}

// Round 18
// 364.015 us; speedup vs baseline: 1.3759x; 1.0005x over previous
//
#include <hip/hip_runtime.h>
#include <stdint.h>

// Workspace layout (bytes):
//   [0, 64Mi)            h: coarse activations [b][cell][ic:32]
//   [64Mi, +512Ki)       maskw: 1 bit per fine voxel, word = (b<<16)|(voxel>>5)
//   [+4B @ CNT_OFF]      counter (compact voxel count)
//   [+1Ki @ BSUM_OFF]    bsum: 512 per-scan-block sums -> exclusive offsets
//   [BASE_OFF, +512Ki)   basew: per-mask-word exclusive prefix (MONOTONIC)
//   [WL_OFF, +1Mi)       wl: compact voxel ids (b<<21|z<<14|y<<7|x), sorted
//   [VALS_OFF, +16Mi)    vals: [oc:16][PITCH] precomputed deconv outputs
#define MASK_OFF  ((size_t)67108864)
#define CNT_OFF   ((size_t)67633152)
#define BSUM_OFF  ((size_t)67633408)
#define BASE_OFF  ((size_t)67637504)
#define WL_OFF    ((size_t)68161792)
#define VALS_OFF  ((size_t)69210368)
#define PITCH     262144
#define NWORDS    131072

typedef float f32x4 __attribute__((ext_vector_type(4)));

__global__ __launch_bounds__(256) void scn_scatter_conv1(
    const float* __restrict__ feat, const float* __restrict__ W1,
    const int* __restrict__ coors, float* __restrict__ h,
    uint32_t* __restrict__ maskw, int npts)
{
    __shared__ float Ws[8 * 16 * 32];
    for (int i = threadIdx.x; i < 4096; i += 256) {
        // W1: [ic:32][cin:16][p:8] -> Ws[p][cin][ic]
        int ic = i >> 7, rem = i & 127, cin = rem >> 3, p = rem & 7;
        Ws[(p << 9) | (cin << 5) | ic] = W1[i];
    }
    __syncthreads();

    int total = npts * 32;
    for (int idx = blockIdx.x * 256 + threadIdx.x; idx < total;
         idx += gridDim.x * 256) {
        int pid = idx >> 5, ic = idx & 31;
        int b = coors[pid * 4 + 0];
        int z = coors[pid * 4 + 1];
        int y = coors[pid * 4 + 2];
        int x = coors[pid * 4 + 3];
        int p = ((z & 1) << 2) | ((y & 1) << 1) | (x & 1);

        const f32x4* f4 = reinterpret_cast<const f32x4*>(feat + pid * 16);
        f32x4 a0 = f4[0], a1 = f4[1], a2 = f4[2], a3 = f4[3];

        const float* w = Ws + (p << 9) + ic;   // stride 32 over cin
        float s = 0.f;
        s += a0[0] * w[0 << 5];   s += a0[1] * w[1 << 5];
        s += a0[2] * w[2 << 5];   s += a0[3] * w[3 << 5];
        s += a1[0] * w[4 << 5];   s += a1[1] * w[5 << 5];
        s += a1[2] * w[6 << 5];   s += a1[3] * w[7 << 5];
        s += a2[0] * w[8 << 5];   s += a2[1] * w[9 << 5];
        s += a2[2] * w[10 << 5];  s += a2[3] * w[11 << 5];
        s += a3[0] * w[12 << 5];  s += a3[1] * w[13 << 5];
        s += a3[2] * w[14 << 5];  s += a3[3] * w[15 << 5];

        int cell = (b << 18) | ((z >> 1) << 12) | ((y >> 1) << 6) | (x >> 1);
        atomicAdd(&h[((size_t)cell << 5) | ic], s);

        if (ic == 0) {
            int voxel = (z << 14) | (y << 7) | x;
            atomicOr(&maskw[(b << 16) | (voxel >> 5)], 1u << (voxel & 31));
        }
    }
}

// ---- 3-kernel exclusive prefix scan over per-word popcounts (monotonic basew)
__global__ __launch_bounds__(256) void scn_scan1(
    const uint32_t* __restrict__ maskw, uint32_t* __restrict__ bsum)
{
    __shared__ uint32_t red[256];
    int t = threadIdx.x;
    red[t] = __popc(maskw[blockIdx.x * 256 + t]);
    __syncthreads();
    for (int s = 128; s > 0; s >>= 1) {
        if (t < s) red[t] += red[t + s];
        __syncthreads();
    }
    if (t == 0) bsum[blockIdx.x] = red[0];
}

__global__ __launch_bounds__(512) void scn_scan2(
    uint32_t* __restrict__ bsum, uint32_t* __restrict__ cnt)
{
    __shared__ uint32_t v[512];
    int t = threadIdx.x;
    v[t] = bsum[t];
    __syncthreads();
    for (int off = 1; off < 512; off <<= 1) {
        uint32_t x = v[t];
        uint32_t y = (t >= off) ? v[t - off] : 0;
        __syncthreads();
        v[t] = x + y;
        __syncthreads();
    }
    bsum[t] = t ? v[t - 1] : 0;        // exclusive
    if (t == 511) *cnt = v[511];
}

__global__ __launch_bounds__(256) void scn_scan3(
    const uint32_t* __restrict__ maskw, const uint32_t* __restrict__ bsum,
    uint32_t* __restrict__ basew, uint32_t* __restrict__ wl)
{
    __shared__ uint32_t v[256];
    int t = threadIdx.x;
    int i = blockIdx.x * 256 + t;
    uint32_t w = maskw[i];
    v[t] = __popc(w);
    __syncthreads();
    for (int off = 1; off < 256; off <<= 1) {
        uint32_t x = v[t];
        uint32_t y = (t >= off) ? v[t - off] : 0;
        __syncthreads();
        v[t] = x + y;
        __syncthreads();
    }
    uint32_t base = bsum[blockIdx.x] + (t ? v[t - 1] : 0);
    basew[i] = base;
    uint32_t vb = (uint32_t)i << 5;    // (b<<21)|(z<<14)|(y<<7)|(x&~31)
    while (w) {
        int bit = __ffs(w) - 1;
        wl[base++] = vb | (uint32_t)bit;
        w &= w - 1;
    }
}

// One thread per compact voxel: load h[cell] ONCE (128 B), compute all 16 oc.
__global__ __launch_bounds__(256) void scn_compute_vals(
    const float* __restrict__ h, const float* __restrict__ W2,
    const uint32_t* __restrict__ wl, const uint32_t* __restrict__ cnt,
    float* __restrict__ vals)
{
    // W2: [oc:16][ic:32][p:8] -> Ws[p*529 + ic*16 + oc]
    __shared__ float Ws[8 * 529];
    for (int i = threadIdx.x; i < 4096; i += 256) {
        int oc = i >> 8, rem = i & 255, ic = rem >> 3, p = rem & 7;
        Ws[p * 529 + (ic << 4) + oc] = W2[i];
    }
    __syncthreads();

    uint32_t n = *cnt;
    uint32_t i = blockIdx.x * 256 + threadIdx.x;
    if (i >= n) return;

    uint32_t v = wl[i];
    int b = v >> 21, z = (v >> 14) & 127, y = (v >> 7) & 127, x = v & 127;
    int p = (((z & 1) ^ 1) << 2) | (((y & 1) ^ 1) << 1) | ((x & 1) ^ 1);
    int cell = (b << 18) | ((z >> 1) << 12) | ((y >> 1) << 6) | (x >> 1);

    const f32x4* hc = reinterpret_cast<const f32x4*>(h + ((size_t)cell << 5));
    f32x4 hv[8];
    #pragma unroll
    for (int q = 0; q < 8; ++q) hv[q] = hc[q];

    const float* wp = Ws + p * 529;
    for (int oc = 0; oc < 16; ++oc) {
        float s = 0.f;
        #pragma unroll
        for (int q = 0; q < 8; ++q) {
            s += hv[q][0] * wp[((4 * q + 0) << 4) + oc];
            s += hv[q][1] * wp[((4 * q + 1) << 4) + oc];
            s += hv[q][2] * wp[((4 * q + 2) << 4) + oc];
            s += hv[q][3] * wp[((4 * q + 3) << 4) + oc];
        }
        vals[(size_t)oc * PITCH + i] = s;
    }
}

// Streaming fill: block = contiguous 2048-float4 span of ONE plane; store loop
// has zero global loads on the hot path. s_vals sized for the REALISTIC case
// (expected ~390 occupied voxels/chunk; 2048 = 4σ headroom) -> 10 KB LDS ->
// 8 blocks/CU (was 4 at 34.8 KB), doubling cross-block stage/store overlap.
// Correctness fallback: n > 2048 (practically impossible) reads vals direct.
__global__ __launch_bounds__(256) void scn_fill_merge(
    const uint32_t* __restrict__ maskw, const uint32_t* __restrict__ basew,
    const float* __restrict__ vals, float* __restrict__ out)
{
    __shared__ uint32_t s_mask[256];
    __shared__ uint32_t s_base[256];
    __shared__ float    s_vals[2048];

    int tid   = threadIdx.x;
    int chunk = blockIdx.x;            // 0..8191
    int chan  = chunk >> 8;            // b*16 + oc
    int c     = chunk & 255;           // which 2048-float4 chunk of the plane
    int b     = chan >> 4;
    int oc    = chan & 15;

    int w0 = (b << 16) | (c << 8);     // first global mask word of this chunk
    s_mask[tid] = maskw[w0 + tid];
    s_base[tid] = basew[w0 + tid];
    __syncthreads();

    uint32_t vbase = s_base[0];
    uint32_t vend  = s_base[255] + __popc(s_mask[255]);
    int n = (int)(vend - vbase);
    const float* voc = vals + ((size_t)oc << 18);   // PITCH = 1<<18
    bool lds_ok = (n <= 2048);
    if (lds_ok)
        for (int i = tid; i < n; i += 256) s_vals[i] = voc[vbase + i];
    __syncthreads();

    f32x4* out4 = reinterpret_cast<f32x4*>(out) + ((size_t)chan << 19)
                + (size_t)c * 2048;
    #pragma unroll
    for (int it = 0; it < 8; ++it) {
        int lv4 = it * 256 + tid;                   // 0..2047
        uint32_t mword = s_mask[lv4 >> 3];
        int bit0 = (lv4 & 7) << 2;
        uint32_t nib = (mword >> bit0) & 0xFu;
        f32x4 r = {0.f, 0.f, 0.f, 0.f};
        if (nib) {
            uint32_t base = s_base[lv4 >> 3] - vbase;
            uint32_t i0 = base + __popc(mword & ((1u << (bit0 + 0)) - 1u));
            uint32_t i1 = base + __popc(mword & ((1u << (bit0 + 1)) - 1u));
            uint32_t i2 = base + __popc(mword & ((1u << (bit0 + 2)) - 1u));
            uint32_t i3 = base + __popc(mword & ((1u << (bit0 + 3)) - 1u));
            if (lds_ok) {
                if (nib & 1u) r[0] = s_vals[i0];
                if (nib & 2u) r[1] = s_vals[i1];
                if (nib & 4u) r[2] = s_vals[i2];
                if (nib & 8u) r[3] = s_vals[i3];
            } else {
                if (nib & 1u) r[0] = voc[vbase + i0];
                if (nib & 2u) r[1] = voc[vbase + i1];
                if (nib & 4u) r[2] = voc[vbase + i2];
                if (nib & 8u) r[3] = voc[vbase + i3];
            }
        }
        out4[lv4] = r;
    }
}

extern "C" void kernel_launch(void* const* d_in, const int* in_sizes, int n_in,
                              void* d_out, int out_size, void* d_ws, size_t ws_size,
                              hipStream_t stream) {
    const float* feat  = (const float*)d_in[0];
    const float* W1    = (const float*)d_in[1];
    const float* W2    = (const float*)d_in[2];
    const int*   coors = (const int*)d_in[3];
    float*       out   = (float*)d_out;

    char* ws = (char*)d_ws;
    float*    h     = (float*)ws;
    uint32_t* maskw = (uint32_t*)(ws + MASK_OFF);
    uint32_t* cnt   = (uint32_t*)(ws + CNT_OFF);
    uint32_t* bsum  = (uint32_t*)(ws + BSUM_OFF);
    uint32_t* basew = (uint32_t*)(ws + BASE_OFF);
    uint32_t* wl    = (uint32_t*)(ws + WL_OFF);
    float*    vals  = (float*)(ws + VALS_OFF);
    int npts = in_sizes[0] / 16;

    // Zero h + maskw (scan kernels fully write cnt/bsum/basew/wl; vals
    // fully written for i < cnt before merge reads them).
    hipMemsetAsync(d_ws, 0, CNT_OFF, stream);

    int t1 = npts * 32;
    int blocks1 = (t1 + 255) / 256;
    if (blocks1 > 4096) blocks1 = 4096;
    scn_scatter_conv1<<<blocks1, 256, 0, stream>>>(feat, W1, coors, h, maskw, npts);

    scn_scan1<<<NWORDS / 256, 256, 0, stream>>>(maskw, bsum);
    scn_scan2<<<1, 512, 0, stream>>>(bsum, cnt);
    scn_scan3<<<NWORDS / 256, 256, 0, stream>>>(maskw, bsum, basew, wl);

    // One thread per compact voxel (cnt <= npts = 200k < 1024*256).
    scn_compute_vals<<<1024, 256, 0, stream>>>(h, W2, wl, cnt, vals);

    // 8192 blocks: one contiguous 2048-float4 plane chunk each.
    scn_fill_merge<<<8192, 256, 0, stream>>>(maskw, basew, vals, out);
}